// Round 5
// baseline (127.515 us; speedup 1.0000x reference)
//
#include <hip/hip_runtime.h>
#include <cmath>

// GRU-D cell: B=16384, F=U=512.
//   prep_pack: xd,hd -> A1=[xd|hd] bf16 (B x 1024); weights -> bf16 B^T
//   gemm3<0>: A1 @ Wzr -> sigmoid -> Zb (bf16), RH = r*hd (bf16)  [256x128 tiles]
//   gemm3<1>: [xd|RH] @ Wht -> tanh, blend with Zb, hd from A1 -> out
// R5: 3-LDS-buffer pipeline (48KB x 3), prefetch depth 2, counted vmcnt(6)
// per tile (never 0 in main loop) -- removes the per-tile full vm-drain stall
// that R4's 2-buffer schedule required. One barrier per tile. XOR-16B swizzle.

typedef __bf16 bf16x8 __attribute__((ext_vector_type(8)));
typedef __bf16 bf16x4 __attribute__((ext_vector_type(4)));
typedef float f32x4 __attribute__((ext_vector_type(4)));

typedef __attribute__((address_space(3))) void lds_vp;
typedef const __attribute__((address_space(1))) void g_vp;

#define VMC(N) asm volatile("s_waitcnt vmcnt(" N ")" ::: "memory")

__device__ __forceinline__ void barrier_() {
  asm volatile("" ::: "memory");
  __builtin_amdgcn_s_barrier();
  asm volatile("" ::: "memory");
}

__device__ __forceinline__ float sigmoidf_(float x) { return 1.f / (1.f + expf(-x)); }

// ---------------- prep + pack (merged) ----------------
__global__ __launch_bounds__(256) void prep_pack_k(
    const float* __restrict__ inp, const float* __restrict__ h_prev,
    const float* __restrict__ gxd, const float* __restrict__ ghd,
    const float* __restrict__ mimp, __bf16* __restrict__ A1,
    const float* __restrict__ Wz, const float* __restrict__ Uz,
    const float* __restrict__ Wr, const float* __restrict__ Ur,
    const float* __restrict__ Wh, const float* __restrict__ Uh,
    __bf16* __restrict__ Wzr, __bf16* __restrict__ Wht) {
  if (blockIdx.x < 8192) {
    int idx = blockIdx.x * 256 + threadIdx.x;
    int row = idx >> 7;
    int c4 = (idx & 127) << 2;
    const float4 x  = *(const float4*)(inp + (size_t)row * 1536 + c4);
    const float4 mm = *(const float4*)(inp + (size_t)row * 1536 + 512 + c4);
    const float4 dt = *(const float4*)(inp + (size_t)row * 1536 + 1024 + c4);
    const float4 gx = *(const float4*)(gxd + c4);
    const float4 gh = *(const float4*)(ghd + c4);
    const float4 mi = *(const float4*)(mimp + c4);
    const float4 hp = *(const float4*)(h_prev + (size_t)row * 512 + c4);
    bf16x4 xo, ho;
#pragma unroll
    for (int j = 0; j < 4; ++j) {
      float xx = ((const float*)&x)[j];
      float m  = ((const float*)&mm)[j];
      float d  = ((const float*)&dt)[j];
      float g  = expf(-fmaxf(0.f, ((const float*)&gx)[j]) * d);
      float xd = m * xx + (1.f - m) * (g * xx + (1.f - g) * ((const float*)&mi)[j]);
      float gg = expf(-fmaxf(0.f, ((const float*)&gh)[j]) * d);
      float hd = gg * ((const float*)&hp)[j];
      xo[j] = (__bf16)xd;
      ho[j] = (__bf16)hd;
    }
    *(bf16x4*)(A1 + (size_t)row * 1024 + c4) = xo;
    *(bf16x4*)(A1 + (size_t)row * 1024 + 512 + c4) = ho;
  } else {
    int id = (blockIdx.x - 8192) * 256 + threadIdx.x;
    if (id < 1024 * 1024) {
      int n = id >> 10, k = id & 1023;
      float v;
      if (n < 512) v = (k < 512) ? Wz[k * 512 + n] : Uz[(k - 512) * 512 + n];
      else         v = (k < 512) ? Wr[k * 512 + (n - 512)] : Ur[(k - 512) * 512 + (n - 512)];
      Wzr[id] = (__bf16)v;
    } else {
      int id2 = id - 1024 * 1024;
      int n = id2 >> 10, k = id2 & 1023;
      float v = (k < 512) ? Wh[k * 512 + n] : Uh[(k - 512) * 512 + n];
      Wht[id2] = (__bf16)v;
    }
  }
}

// ---------------- 3-buffer pipelined GEMM (BM=256, BN=128, BK=64) ----------------
// stage one 8-row x 128B group: linear LDS dest, inverse-swizzled global src
// (LDS[r][u] (16B units) holds global (r, u ^ (r&7))).
__device__ __forceinline__ void stage_q(const char* g, int ldb, char* ldst,
                                        int rowbase, int lane) {
  int r = rowbase + (lane >> 3);
  int c = (((lane & 7) ^ (lane >> 3)) << 4);
  __builtin_amdgcn_global_load_lds((g_vp*)(g + (size_t)r * ldb + c),
                                   (lds_vp*)(ldst + rowbase * 128), 16, 0, 0);
}

template <int MODE>
__global__ __launch_bounds__(512, 1) void gemm3_k(
    const __bf16* __restrict__ A1, const __bf16* __restrict__ RH,
    const __bf16* __restrict__ Bt,
    __bf16* __restrict__ Zb, __bf16* __restrict__ RHout,
    const float* __restrict__ bza, const float* __restrict__ bzb,
    float* __restrict__ out) {
  constexpr int SBUF = 3072;                 // 16B units: A 2048 | B 1024
  __shared__ bf16x8 ldsv[3 * SBUF];          // 144 KB
  constexpr int NT = 16;
  constexpr int NBN = (MODE == 0) ? 8 : 4;   // N = 1024 / 512, BN=128
  constexpr int CPX = ((MODE == 0) ? 512 : 256) / 8;

  int bid = blockIdx.x;
  int swz = (bid & 7) * CPX + (bid >> 3);    // bijective XCD swizzle
  int bm = swz / NBN, bn = swz % NBN;
  int tid = threadIdx.x, lane = tid & 63, wid = tid >> 6;
  int wm = wid >> 2, wn = wid & 3;           // wave tile: 128 x 32

  auto stage = [&](int t, int buf) {
    const char* gA;
    int ldbA;
    if (MODE == 0 || t < 8) {
      gA = (const char*)A1 + (size_t)bm * 256 * 2048 + t * 128;
      ldbA = 2048;
    } else {
      gA = (const char*)RH + (size_t)bm * 256 * 1024 + (t - 8) * 128;
      ldbA = 1024;
    }
    char* ldstA = (char*)(ldsv + buf * SBUF);
#pragma unroll
    for (int i = 0; i < 4; ++i) stage_q(gA, ldbA, ldstA, i * 64 + wid * 8, lane);
    const char* gB = (const char*)Bt + (size_t)bn * 128 * 2048 + t * 128;
    char* ldstB = (char*)(ldsv + buf * SBUF + 2048);
#pragma unroll
    for (int i = 0; i < 2; ++i) stage_q(gB, 2048, ldstB, i * 64 + wid * 8, lane);
  };  // 6 global_load_lds per wave per tile

  // swizzled read cols (16B units)
  int colx0 = (lane >> 4) ^ (lane & 7);
  int colx1 = ((lane >> 4) + 4) ^ (lane & 7);
  int aB = wm * 1024 + (lane & 15) * 8;      // + mi*128 + colx
  int bB = 2048 + wn * 256 + (lane & 15) * 8;  // + ni*128 + colx

  f32x4 acc[8][2] = {};

  stage(0, 0);
  stage(1, 1);
  VMC("6");
  barrier_();

  for (int t = 0; t < NT; ++t) {
    int base = (t % 3) * SBUF;
    if (t + 2 < NT) stage(t + 2, (t + 2) % 3);

    bf16x8 bf[4];
#pragma unroll
    for (int ni = 0; ni < 2; ++ni) {
      bf[ni * 2 + 0] = ldsv[base + bB + ni * 128 + colx0];
      bf[ni * 2 + 1] = ldsv[base + bB + ni * 128 + colx1];
    }
    __builtin_amdgcn_s_setprio(1);
#pragma unroll
    for (int mi = 0; mi < 8; ++mi) {
      bf16x8 a0 = ldsv[base + aB + mi * 128 + colx0];
      bf16x8 a1 = ldsv[base + aB + mi * 128 + colx1];
#pragma unroll
      for (int ni = 0; ni < 2; ++ni) {
        acc[mi][ni] = __builtin_amdgcn_mfma_f32_16x16x32_bf16(a0, bf[ni * 2 + 0],
                                                              acc[mi][ni], 0, 0, 0);
        acc[mi][ni] = __builtin_amdgcn_mfma_f32_16x16x32_bf16(a1, bf[ni * 2 + 1],
                                                              acc[mi][ni], 0, 0, 0);
      }
    }
    __builtin_amdgcn_s_setprio(0);

    // counted wait: drain tile t+1's 6 loads, leave tile t+2's 6 in flight
    if (t + 2 < NT) { VMC("6"); } else if (t + 1 < NT) { VMC("0"); }
    if (t + 1 < NT) barrier_();
  }

  // ---------------- epilogue ----------------
  int col16 = lane & 15, rgrp = lane >> 4;
#pragma unroll
  for (int m = 0; m < 8; ++m) {
    int grow0 = bm * 256 + wm * 128 + m * 16 + rgrp * 4;
#pragma unroll
    for (int n = 0; n < 2; ++n) {
      int gc = bn * 128 + wn * 32 + n * 16 + col16;
      if constexpr (MODE == 0) {
        if (bn < 4) {  // z columns (block-uniform: 128 | 512)
          float b = bza[gc];
#pragma unroll
          for (int j = 0; j < 4; ++j) {
            float z = sigmoidf_(acc[m][n][j] + b);
            Zb[(size_t)(grow0 + j) * 512 + gc] = (__bf16)z;
          }
        } else {       // r columns
          int c = gc - 512;
          float b = bzb[c];
#pragma unroll
          for (int j = 0; j < 4; ++j) {
            int grow = grow0 + j;
            float r = sigmoidf_(acc[m][n][j] + b);
            float hd = (float)A1[(size_t)grow * 1024 + 512 + c];
            RHout[(size_t)grow * 512 + c] = (__bf16)(r * hd);
          }
        }
      } else {
        float b = bza[gc];
#pragma unroll
        for (int j = 0; j < 4; ++j) {
          int grow = grow0 + j;
          float hh = tanhf(acc[m][n][j] + b);
          float hd = (float)A1[(size_t)grow * 1024 + 512 + gc];
          float z = (float)Zb[(size_t)grow * 512 + gc];
          out[(size_t)grow * 512 + gc] = (1.f - z) * hd + z * hh;
        }
      }
    }
  }
}

// ---------------- launch ----------------
extern "C" void kernel_launch(void* const* d_in, const int* in_sizes, int n_in,
                              void* d_out, int out_size, void* d_ws, size_t ws_size,
                              hipStream_t stream) {
  const float* inputs = (const float*)d_in[0];
  const float* h_prev = (const float*)d_in[1];
  const float* W_z = (const float*)d_in[2];
  const float* U_z = (const float*)d_in[3];
  const float* b_z = (const float*)d_in[4];
  const float* W_r = (const float*)d_in[5];
  const float* U_r = (const float*)d_in[6];
  const float* b_r = (const float*)d_in[7];
  const float* W_h = (const float*)d_in[8];
  const float* U_h = (const float*)d_in[9];
  const float* b_h = (const float*)d_in[10];
  const float* gxd = (const float*)d_in[11];
  const float* ghd = (const float*)d_in[12];
  const float* mimp = (const float*)d_in[13];
  float* out = (float*)d_out;

  char* ws = (char*)d_ws;
  __bf16* A1  = (__bf16*)(ws);                  // 16384x1024 bf16 = 32MB
  __bf16* RH  = (__bf16*)(ws + 33554432);       // 16384x512 bf16 = 16MB
  __bf16* Zb  = (__bf16*)(ws + 50331648);       // 16384x512 bf16 = 16MB
  __bf16* Wzr = (__bf16*)(ws + 67108864);       // 1024x1024 bf16 = 2MB
  __bf16* Wht = (__bf16*)(ws + 69206016);       // 512x1024 bf16  = 1MB

  prep_pack_k<<<14336, 256, 0, stream>>>(inputs, h_prev, gxd, ghd, mimp, A1,
                                         W_z, U_z, W_r, U_r, W_h, U_h, Wzr, Wht);
  gemm3_k<0><<<512, 512, 0, stream>>>(A1, RH, Wzr, Zb, RH, b_z, b_r, nullptr);
  gemm3_k<1><<<256, 512, 0, stream>>>(A1, RH, Wht, Zb, nullptr, b_h, nullptr, out);
}

// Round 7
// 124.607 us; speedup vs baseline: 1.0233x; 1.0233x over previous
//
#include <hip/hip_runtime.h>
#include <cmath>

// GRU-D cell: B=16384, F=U=512.
//   prep_pack: xd,hd -> A1=[xd|hd] bf16 (B x 1024); weights -> bf16 B^T
//   gemm4<0>: A1 @ Wzr -> sigmoid -> Zb (bf16), RH = r*hd (bf16)  [256x128]
//   gemm4<1>: [xd|RH] @ Wht -> tanh, blend with Zb, hd from A1 -> out [256x64]
// R7 = R6 with the MODE0 B-staging coverage bug fixed (B region is 512 units;
// R6 staged only 256, twice). 2 blocks/CU (72/60KB LDS, launch_bounds(512,2)),
// BK=32, row-pair-packed LDS (two 64B rows per 128B LDS row), XOR swizzle,
// 3 buffers, counted vmcnt.

typedef __bf16 bf16x8 __attribute__((ext_vector_type(8)));
typedef __bf16 bf16x4 __attribute__((ext_vector_type(4)));
typedef float f32x4 __attribute__((ext_vector_type(4)));

typedef __attribute__((address_space(3))) void lds_vp;
typedef const __attribute__((address_space(1))) void g_vp;

#define VMC(N) asm volatile("s_waitcnt vmcnt(" N ")" ::: "memory")

__device__ __forceinline__ void barrier_() {
  asm volatile("" ::: "memory");
  __builtin_amdgcn_s_barrier();
  asm volatile("" ::: "memory");
}

__device__ __forceinline__ float sigmoidf_(float x) { return 1.f / (1.f + expf(-x)); }

// ---------------- prep + pack (merged) ----------------
__global__ __launch_bounds__(256) void prep_pack_k(
    const float* __restrict__ inp, const float* __restrict__ h_prev,
    const float* __restrict__ gxd, const float* __restrict__ ghd,
    const float* __restrict__ mimp, __bf16* __restrict__ A1,
    const float* __restrict__ Wz, const float* __restrict__ Uz,
    const float* __restrict__ Wr, const float* __restrict__ Ur,
    const float* __restrict__ Wh, const float* __restrict__ Uh,
    __bf16* __restrict__ Wzr, __bf16* __restrict__ Wht) {
  if (blockIdx.x < 8192) {
    int idx = blockIdx.x * 256 + threadIdx.x;
    int row = idx >> 7;
    int c4 = (idx & 127) << 2;
    const float4 x  = *(const float4*)(inp + (size_t)row * 1536 + c4);
    const float4 mm = *(const float4*)(inp + (size_t)row * 1536 + 512 + c4);
    const float4 dt = *(const float4*)(inp + (size_t)row * 1536 + 1024 + c4);
    const float4 gx = *(const float4*)(gxd + c4);
    const float4 gh = *(const float4*)(ghd + c4);
    const float4 mi = *(const float4*)(mimp + c4);
    const float4 hp = *(const float4*)(h_prev + (size_t)row * 512 + c4);
    bf16x4 xo, ho;
#pragma unroll
    for (int j = 0; j < 4; ++j) {
      float xx = ((const float*)&x)[j];
      float m  = ((const float*)&mm)[j];
      float d  = ((const float*)&dt)[j];
      float g  = expf(-fmaxf(0.f, ((const float*)&gx)[j]) * d);
      float xd = m * xx + (1.f - m) * (g * xx + (1.f - g) * ((const float*)&mi)[j]);
      float gg = expf(-fmaxf(0.f, ((const float*)&gh)[j]) * d);
      float hd = gg * ((const float*)&hp)[j];
      xo[j] = (__bf16)xd;
      ho[j] = (__bf16)hd;
    }
    *(bf16x4*)(A1 + (size_t)row * 1024 + c4) = xo;
    *(bf16x4*)(A1 + (size_t)row * 1024 + 512 + c4) = ho;
  } else {
    int id = (blockIdx.x - 8192) * 256 + threadIdx.x;
    if (id < 1024 * 1024) {
      int n = id >> 10, k = id & 1023;
      float v;
      if (n < 512) v = (k < 512) ? Wz[k * 512 + n] : Uz[(k - 512) * 512 + n];
      else         v = (k < 512) ? Wr[k * 512 + (n - 512)] : Ur[(k - 512) * 512 + (n - 512)];
      Wzr[id] = (__bf16)v;
    } else {
      int id2 = id - 1024 * 1024;
      int n = id2 >> 10, k = id2 & 1023;
      float v = (k < 512) ? Wh[k * 512 + n] : Uh[(k - 512) * 512 + n];
      Wht[id2] = (__bf16)v;
    }
  }
}

// ---------------- 3-buffer, 2-blocks/CU GEMM (BM=256, BK=32) ----------------
// LDS packed layout (16B units): logical element (row m, 16B k-chunk ku in 0..3)
// stored at unit (m>>1)*8 + (((m&1)*4 + ku) ^ ((m>>1)&7)).
// Staging writes linear units; per-lane global source address applies the
// inverse map (rule 21: swizzle on BOTH source and read, LDS dest linear).

template <int MODE>
__global__ __launch_bounds__(512, 2) void gemm4_k(
    const __bf16* __restrict__ A1, const __bf16* __restrict__ RH,
    const __bf16* __restrict__ Bt,
    __bf16* __restrict__ Zb, __bf16* __restrict__ RHout,
    const float* __restrict__ bza, const float* __restrict__ bzb,
    float* __restrict__ out) {
  constexpr int NI = (MODE == 0) ? 4 : 2;     // n-frags per wave
  constexpr int BN = NI * 32;                 // 128 / 64
  constexpr int SBUF = 1024 + BN * 4;         // 16B units: A 1024 | B BN*4
  __shared__ bf16x8 ldsv[3 * SBUF];           // 72KB / 60KB
  constexpr int NT = 32;                      // K=1024, BK=32

  int bid = blockIdx.x;
  int swz = (bid & 7) * 64 + (bid >> 3);      // bijective XCD swizzle (512=8*64)
  int bm = swz >> 3, bn = swz & 7;
  int tid = threadIdx.x, lane = tid & 63, wid = tid >> 6;
  int wm = wid >> 1, wn = wid & 1;            // 4M x 2N waves: 64 x (NI*16) tile

  // per-lane staging source offsets (inverse of packed-swizzle map)
  auto inv = [&](int U, int ldb) {
    int r = U >> 3, s = (U & 7) ^ (r & 7);
    return (2 * r + (s >> 2)) * ldb + (s & 3) * 16;  // bytes
  };
  int UA0 = wid * 128 + lane, UA1 = UA0 + 64;
  int UB = (MODE == 0) ? (wid * 64 + lane) : ((wid & 3) * 64 + lane);
  int offA0 = inv(UA0, 2048), offA1 = inv(UA1, 2048);
  int offA0r = inv(UA0, 1024), offA1r = inv(UA1, 1024);  // MODE1 RH half
  int offB = inv(UB, 2048);
  int ldsB = (MODE == 0) ? (wid * 64) : ((wid & 3) * 64);  // wave-uniform

  auto stage = [&](int t, int buf) {
    const char* gA;
    int oA0, oA1;
    if (MODE == 0 || t < 16) {
      gA = (const char*)A1 + (size_t)bm * 256 * 2048 + t * 64;
      oA0 = offA0; oA1 = offA1;
    } else {
      gA = (const char*)RH + (size_t)bm * 256 * 1024 + (t - 16) * 64;
      oA0 = offA0r; oA1 = offA1r;
    }
    __builtin_amdgcn_global_load_lds((g_vp*)(gA + oA0),
        (lds_vp*)(ldsv + buf * SBUF + wid * 128), 16, 0, 0);
    __builtin_amdgcn_global_load_lds((g_vp*)(gA + oA1),
        (lds_vp*)(ldsv + buf * SBUF + wid * 128 + 64), 16, 0, 0);
    if (MODE == 0 || wid < 4) {
      const char* gB = (const char*)Bt + (size_t)bn * BN * 2048 + t * 64;
      __builtin_amdgcn_global_load_lds((g_vp*)(gB + offB),
          (lds_vp*)(ldsv + buf * SBUF + 1024 + ldsB), 16, 0, 0);
    }
  };
  // loads per wave per tile: MODE0: 3; MODE1: wid<4 ? 3 : 2
#define VMCW(C3, C2)                                   \
  do {                                                 \
    if (MODE == 0 || wid < 4) { VMC(C3); } else { VMC(C2); } \
  } while (0)

  // fragment read bases (16B units), loop-invariant
  int lr = (lane & 15) >> 1;
  int lo = ((lane & 1) << 2) | (lane >> 4);
  int aoff = lr * 8 + (lo ^ lr);
  int aB = wm * 256 + aoff;                   // + mf*64
  int bB = 1024 + wn * (NI * 64) + aoff;      // + nf*64

  f32x4 acc[4][NI] = {};

  stage(0, 0);
  stage(1, 1);
  VMCW("3", "2");
  barrier_();

  int rb = 0, sb = 2;
  for (int t = 0; t < NT; ++t) {
    int base = rb * SBUF;
    if (t + 2 < NT) stage(t + 2, sb);

    bf16x8 bf[NI];
#pragma unroll
    for (int nf = 0; nf < NI; ++nf) bf[nf] = ldsv[base + bB + nf * 64];
    __builtin_amdgcn_s_setprio(1);
#pragma unroll
    for (int mf = 0; mf < 4; ++mf) {
      bf16x8 a = ldsv[base + aB + mf * 64];
#pragma unroll
      for (int nf = 0; nf < NI; ++nf)
        acc[mf][nf] = __builtin_amdgcn_mfma_f32_16x16x32_bf16(a, bf[nf],
                                                              acc[mf][nf], 0, 0, 0);
    }
    __builtin_amdgcn_s_setprio(0);

    if (t + 2 < NT) { VMCW("3", "2"); }
    else if (t + 1 < NT) { VMC("0"); }
    if (t + 1 < NT) barrier_();
    rb = (rb == 2) ? 0 : rb + 1;
    sb = (sb == 2) ? 0 : sb + 1;
  }

  // ---------------- epilogue ----------------
  int col16 = lane & 15, rgrp = lane >> 4;
#pragma unroll
  for (int mf = 0; mf < 4; ++mf) {
    int grow0 = bm * 256 + wm * 64 + mf * 16 + rgrp * 4;
#pragma unroll
    for (int nf = 0; nf < NI; ++nf) {
      int gc = bn * BN + wn * (NI * 16) + nf * 16 + col16;
      if constexpr (MODE == 0) {
        if (bn < 4) {  // z columns (block-uniform: BN=128, cols<512)
          float b = bza[gc];
#pragma unroll
          for (int j = 0; j < 4; ++j) {
            float z = sigmoidf_(acc[mf][nf][j] + b);
            Zb[(size_t)(grow0 + j) * 512 + gc] = (__bf16)z;
          }
        } else {       // r columns
          int c = gc - 512;
          float b = bzb[c];
#pragma unroll
          for (int j = 0; j < 4; ++j) {
            int grow = grow0 + j;
            float r = sigmoidf_(acc[mf][nf][j] + b);
            float hd = (float)A1[(size_t)grow * 1024 + 512 + c];
            RHout[(size_t)grow * 512 + c] = (__bf16)(r * hd);
          }
        }
      } else {
        float b = bza[gc];
#pragma unroll
        for (int j = 0; j < 4; ++j) {
          int grow = grow0 + j;
          float hh = tanhf(acc[mf][nf][j] + b);
          float hd = (float)A1[(size_t)grow * 1024 + 512 + gc];
          float z = (float)Zb[(size_t)grow * 512 + gc];
          out[(size_t)grow * 512 + gc] = (1.f - z) * hd + z * hh;
        }
      }
    }
  }
}

// ---------------- launch ----------------
extern "C" void kernel_launch(void* const* d_in, const int* in_sizes, int n_in,
                              void* d_out, int out_size, void* d_ws, size_t ws_size,
                              hipStream_t stream) {
  const float* inputs = (const float*)d_in[0];
  const float* h_prev = (const float*)d_in[1];
  const float* W_z = (const float*)d_in[2];
  const float* U_z = (const float*)d_in[3];
  const float* b_z = (const float*)d_in[4];
  const float* W_r = (const float*)d_in[5];
  const float* U_r = (const float*)d_in[6];
  const float* b_r = (const float*)d_in[7];
  const float* W_h = (const float*)d_in[8];
  const float* U_h = (const float*)d_in[9];
  const float* b_h = (const float*)d_in[10];
  const float* gxd = (const float*)d_in[11];
  const float* ghd = (const float*)d_in[12];
  const float* mimp = (const float*)d_in[13];
  float* out = (float*)d_out;

  char* ws = (char*)d_ws;
  __bf16* A1  = (__bf16*)(ws);                  // 16384x1024 bf16 = 32MB
  __bf16* RH  = (__bf16*)(ws + 33554432);       // 16384x512 bf16 = 16MB
  __bf16* Zb  = (__bf16*)(ws + 50331648);       // 16384x512 bf16 = 16MB
  __bf16* Wzr = (__bf16*)(ws + 67108864);       // 1024x1024 bf16 = 2MB
  __bf16* Wht = (__bf16*)(ws + 69206016);       // 512x1024 bf16  = 1MB

  prep_pack_k<<<14336, 256, 0, stream>>>(inputs, h_prev, gxd, ghd, mimp, A1,
                                         W_z, U_z, W_r, U_r, W_h, U_h, Wzr, Wht);
  gemm4_k<0><<<512, 512, 0, stream>>>(A1, RH, Wzr, Zb, RH, b_z, b_r, nullptr);
  gemm4_k<1><<<512, 512, 0, stream>>>(A1, RH, Wht, Zb, nullptr, b_h, nullptr, out);
}

// Round 8
// 122.754 us; speedup vs baseline: 1.0388x; 1.0151x over previous
//
#include <hip/hip_runtime.h>
#include <cmath>

// GRU-D cell: B=16384, F=U=512.
//   prep_pack: xd,hd -> A1=[xd|hd] bf16 (B x 1024); weights -> bf16 B^T
//   gemm5<0>: A1 @ Wzr -> sigmoid -> Zb (bf16), RH = r*hd (bf16)  [256x256]
//   gemm5<1>: [xd|RH] @ Wht -> tanh, blend with Zb, hd from A1 -> out [256x128]
// R8: R7 evidence -- per-block time is FIXED (gemm1 at half FLOPs = same 61us
// as gemm0): per-tile cost is vmcnt/barrier/A-stage bound, MFMA count free.
// So widen BN (gemm0 128->256, gemm1 64->128): grid 512->256 = ONE round of
// blocks instead of two, same fixed cost. BK=32, 3 buffers, counted vmcnt,
// row-pair-packed XOR-swizzled LDS (R7-verified).

typedef __bf16 bf16x8 __attribute__((ext_vector_type(8)));
typedef __bf16 bf16x4 __attribute__((ext_vector_type(4)));
typedef float f32x4 __attribute__((ext_vector_type(4)));

typedef __attribute__((address_space(3))) void lds_vp;
typedef const __attribute__((address_space(1))) void g_vp;

#define VMC(N) asm volatile("s_waitcnt vmcnt(" N ")" ::: "memory")

__device__ __forceinline__ void barrier_() {
  asm volatile("" ::: "memory");
  __builtin_amdgcn_s_barrier();
  asm volatile("" ::: "memory");
}

__device__ __forceinline__ float sigmoidf_(float x) { return 1.f / (1.f + expf(-x)); }

// ---------------- prep + pack (merged) ----------------
__global__ __launch_bounds__(256) void prep_pack_k(
    const float* __restrict__ inp, const float* __restrict__ h_prev,
    const float* __restrict__ gxd, const float* __restrict__ ghd,
    const float* __restrict__ mimp, __bf16* __restrict__ A1,
    const float* __restrict__ Wz, const float* __restrict__ Uz,
    const float* __restrict__ Wr, const float* __restrict__ Ur,
    const float* __restrict__ Wh, const float* __restrict__ Uh,
    __bf16* __restrict__ Wzr, __bf16* __restrict__ Wht) {
  if (blockIdx.x < 8192) {
    int idx = blockIdx.x * 256 + threadIdx.x;
    int row = idx >> 7;
    int c4 = (idx & 127) << 2;
    const float4 x  = *(const float4*)(inp + (size_t)row * 1536 + c4);
    const float4 mm = *(const float4*)(inp + (size_t)row * 1536 + 512 + c4);
    const float4 dt = *(const float4*)(inp + (size_t)row * 1536 + 1024 + c4);
    const float4 gx = *(const float4*)(gxd + c4);
    const float4 gh = *(const float4*)(ghd + c4);
    const float4 mi = *(const float4*)(mimp + c4);
    const float4 hp = *(const float4*)(h_prev + (size_t)row * 512 + c4);
    bf16x4 xo, ho;
#pragma unroll
    for (int j = 0; j < 4; ++j) {
      float xx = ((const float*)&x)[j];
      float m  = ((const float*)&mm)[j];
      float d  = ((const float*)&dt)[j];
      float g  = expf(-fmaxf(0.f, ((const float*)&gx)[j]) * d);
      float xd = m * xx + (1.f - m) * (g * xx + (1.f - g) * ((const float*)&mi)[j]);
      float gg = expf(-fmaxf(0.f, ((const float*)&gh)[j]) * d);
      float hd = gg * ((const float*)&hp)[j];
      xo[j] = (__bf16)xd;
      ho[j] = (__bf16)hd;
    }
    *(bf16x4*)(A1 + (size_t)row * 1024 + c4) = xo;
    *(bf16x4*)(A1 + (size_t)row * 1024 + 512 + c4) = ho;
  } else {
    int id = (blockIdx.x - 8192) * 256 + threadIdx.x;
    if (id < 1024 * 1024) {
      int n = id >> 10, k = id & 1023;
      float v;
      if (n < 512) v = (k < 512) ? Wz[k * 512 + n] : Uz[(k - 512) * 512 + n];
      else         v = (k < 512) ? Wr[k * 512 + (n - 512)] : Ur[(k - 512) * 512 + (n - 512)];
      Wzr[id] = (__bf16)v;
    } else {
      int id2 = id - 1024 * 1024;
      int n = id2 >> 10, k = id2 & 1023;
      float v = (k < 512) ? Wh[k * 512 + n] : Uh[(k - 512) * 512 + n];
      Wht[id2] = (__bf16)v;
    }
  }
}

// ---------------- 3-buffer GEMM (BM=256, BK=32, one block-round) ----------------
// LDS packed layout (16B units): logical element (row m, 16B k-chunk ku in 0..3)
// stored at unit (m>>1)*8 + (((m&1)*4 + ku) ^ ((m>>1)&7)).
// Staging writes linear units; per-lane global source applies the inverse map.

template <int MODE>
__global__ __launch_bounds__(512, 1) void gemm5_k(
    const __bf16* __restrict__ A1, const __bf16* __restrict__ RH,
    const __bf16* __restrict__ Bt,
    __bf16* __restrict__ Zb, __bf16* __restrict__ RHout,
    const float* __restrict__ bza, const float* __restrict__ bzb,
    float* __restrict__ out) {
  constexpr int NI = (MODE == 0) ? 8 : 4;     // n-frags per wave
  constexpr int BN = NI * 32;                 // 256 / 128
  constexpr int BUNITS = BN * 4;              // B 16B-units per tile
  constexpr int SBUF = 1024 + BUNITS;         // A 1024 | B
  __shared__ bf16x8 ldsv[3 * SBUF];           // 96KB / 72KB
  constexpr int NT = 32;                      // K=1024, BK=32
  constexpr int NLD = (MODE == 0) ? 4 : 3;    // gload_lds per wave per tile
#define VMC_STEADY() do { if constexpr (MODE == 0) { VMC("4"); } else { VMC("3"); } } while (0)

  int bid = blockIdx.x;
  int swz = (bid & 7) * 32 + (bid >> 3);      // bijective XCD swizzle (256=8*32)
  int bm = swz >> 2, bn = swz & 3;            // 64 x 4
  int tid = threadIdx.x, lane = tid & 63, wid = tid >> 6;
  int wm = wid >> 1, wn = wid & 1;            // 4M x 2N waves: 64 x (NI*16)

  // per-lane staging source offsets (inverse of packed-swizzle map)
  auto inv = [&](int U, int ldb) {
    int r = U >> 3, s = (U & 7) ^ (r & 7);
    return (2 * r + (s >> 2)) * ldb + (s & 3) * 16;  // bytes
  };
  int UA0 = wid * 128 + lane, UA1 = UA0 + 64;
  int offA0 = inv(UA0, 2048), offA1 = inv(UA1, 2048);
  int offA0r = inv(UA0, 1024), offA1r = inv(UA1, 1024);  // MODE1 RH half
  int UB0 = (MODE == 0) ? (wid * 128 + lane) : (wid * 64 + lane);
  int offB0 = inv(UB0, 2048);
  int offB1 = (MODE == 0) ? inv(UB0 + 64, 2048) : 0;
  int ldsB = (MODE == 0) ? (wid * 128) : (wid * 64);   // wave-uniform

  auto stage = [&](int t, int buf) {
    const char* gA;
    int oA0, oA1;
    if (MODE == 0 || t < 16) {
      gA = (const char*)A1 + (size_t)bm * 256 * 2048 + t * 64;
      oA0 = offA0; oA1 = offA1;
    } else {
      gA = (const char*)RH + (size_t)bm * 256 * 1024 + (t - 16) * 64;
      oA0 = offA0r; oA1 = offA1r;
    }
    __builtin_amdgcn_global_load_lds((g_vp*)(gA + oA0),
        (lds_vp*)(ldsv + buf * SBUF + wid * 128), 16, 0, 0);
    __builtin_amdgcn_global_load_lds((g_vp*)(gA + oA1),
        (lds_vp*)(ldsv + buf * SBUF + wid * 128 + 64), 16, 0, 0);
    const char* gB = (const char*)Bt + (size_t)bn * BN * 2048 + t * 64;
    __builtin_amdgcn_global_load_lds((g_vp*)(gB + offB0),
        (lds_vp*)(ldsv + buf * SBUF + 1024 + ldsB), 16, 0, 0);
    if constexpr (MODE == 0) {
      __builtin_amdgcn_global_load_lds((g_vp*)(gB + offB1),
          (lds_vp*)(ldsv + buf * SBUF + 1024 + ldsB + 64), 16, 0, 0);
    }
  };

  // fragment read bases (16B units), loop-invariant
  int lr = (lane & 15) >> 1;
  int lo = ((lane & 1) << 2) | (lane >> 4);
  int aoff = lr * 8 + (lo ^ lr);
  int aB = wm * 256 + aoff;                   // + mf*64
  int bB = 1024 + wn * (NI * 64) + aoff;      // + nf*64

  f32x4 acc[4][NI] = {};

  stage(0, 0);
  stage(1, 1);
  VMC_STEADY();
  barrier_();

  int rb = 0, sb = 2;
  for (int t = 0; t < NT; ++t) {
    int base = rb * SBUF;
    if (t + 2 < NT) stage(t + 2, sb);

    bf16x8 bf[NI];
#pragma unroll
    for (int nf = 0; nf < NI; ++nf) bf[nf] = ldsv[base + bB + nf * 64];
    __builtin_amdgcn_s_setprio(1);
#pragma unroll
    for (int mf = 0; mf < 4; ++mf) {
      bf16x8 a = ldsv[base + aB + mf * 64];
#pragma unroll
      for (int nf = 0; nf < NI; ++nf)
        acc[mf][nf] = __builtin_amdgcn_mfma_f32_16x16x32_bf16(a, bf[nf],
                                                              acc[mf][nf], 0, 0, 0);
    }
    __builtin_amdgcn_s_setprio(0);

    if (t + 2 < NT) { VMC_STEADY(); }
    else if (t + 1 < NT) { VMC("0"); }
    if (t + 1 < NT) barrier_();
    rb = (rb == 2) ? 0 : rb + 1;
    sb = (sb == 2) ? 0 : sb + 1;
  }

  // ---------------- epilogue ----------------
  int col16 = lane & 15, rgrp = lane >> 4;
#pragma unroll
  for (int mf = 0; mf < 4; ++mf) {
    int grow0 = bm * 256 + wm * 64 + mf * 16 + rgrp * 4;
#pragma unroll
    for (int nf = 0; nf < NI; ++nf) {
      int gc = bn * BN + wn * (NI * 16) + nf * 16 + col16;
      if constexpr (MODE == 0) {
        if (gc < 512) {  // z columns (nf-uniform: NI*16 divides 512 boundary)
          float b = bza[gc];
#pragma unroll
          for (int j = 0; j < 4; ++j) {
            float z = sigmoidf_(acc[mf][nf][j] + b);
            Zb[(size_t)(grow0 + j) * 512 + gc] = (__bf16)z;
          }
        } else {       // r columns
          int c = gc - 512;
          float b = bzb[c];
#pragma unroll
          for (int j = 0; j < 4; ++j) {
            int grow = grow0 + j;
            float r = sigmoidf_(acc[mf][nf][j] + b);
            float hd = (float)A1[(size_t)grow * 1024 + 512 + c];
            RHout[(size_t)grow * 512 + c] = (__bf16)(r * hd);
          }
        }
      } else {
        float b = bza[gc];
#pragma unroll
        for (int j = 0; j < 4; ++j) {
          int grow = grow0 + j;
          float hh = tanhf(acc[mf][nf][j] + b);
          float hd = (float)A1[(size_t)grow * 1024 + 512 + gc];
          float z = (float)Zb[(size_t)grow * 512 + gc];
          out[(size_t)grow * 512 + gc] = (1.f - z) * hd + z * hh;
        }
      }
    }
  }
}

// ---------------- launch ----------------
extern "C" void kernel_launch(void* const* d_in, const int* in_sizes, int n_in,
                              void* d_out, int out_size, void* d_ws, size_t ws_size,
                              hipStream_t stream) {
  const float* inputs = (const float*)d_in[0];
  const float* h_prev = (const float*)d_in[1];
  const float* W_z = (const float*)d_in[2];
  const float* U_z = (const float*)d_in[3];
  const float* b_z = (const float*)d_in[4];
  const float* W_r = (const float*)d_in[5];
  const float* U_r = (const float*)d_in[6];
  const float* b_r = (const float*)d_in[7];
  const float* W_h = (const float*)d_in[8];
  const float* U_h = (const float*)d_in[9];
  const float* b_h = (const float*)d_in[10];
  const float* gxd = (const float*)d_in[11];
  const float* ghd = (const float*)d_in[12];
  const float* mimp = (const float*)d_in[13];
  float* out = (float*)d_out;

  char* ws = (char*)d_ws;
  __bf16* A1  = (__bf16*)(ws);                  // 16384x1024 bf16 = 32MB
  __bf16* RH  = (__bf16*)(ws + 33554432);       // 16384x512 bf16 = 16MB
  __bf16* Zb  = (__bf16*)(ws + 50331648);       // 16384x512 bf16 = 16MB
  __bf16* Wzr = (__bf16*)(ws + 67108864);       // 1024x1024 bf16 = 2MB
  __bf16* Wht = (__bf16*)(ws + 69206016);       // 512x1024 bf16  = 1MB

  prep_pack_k<<<14336, 256, 0, stream>>>(inputs, h_prev, gxd, ghd, mimp, A1,
                                         W_z, U_z, W_r, U_r, W_h, U_h, Wzr, Wht);
  gemm5_k<0><<<256, 512, 0, stream>>>(A1, RH, Wzr, Zb, RH, b_z, b_r, nullptr);
  gemm5_k<1><<<256, 512, 0, stream>>>(A1, RH, Wht, Zb, nullptr, b_h, nullptr, out);
}

// Round 9
// 118.887 us; speedup vs baseline: 1.0726x; 1.0325x over previous
//
#include <hip/hip_runtime.h>
#include <cmath>

// GRU-D cell: B=16384, F=U=512.
//   prep_pack: xd,hd -> A1=[xd|hd] bf16 (B x 1024); weights -> bf16 B^T
//   gemm5<0>: A1 @ Wzr -> sigmoid -> Zb (bf16), RH = r*hd (bf16)  [256x256]
//   gemm5<1>: [xd|RH] @ Wht -> tanh, blend with Zb, hd from A1 -> out [256x128]
// R9: prep_pack rewrite. R8 evidence: VGPR_Count=24 serialized the 7 float4
// loads (1 load in flight/wave -> 1.2 TB/s). Now 8 cols/thread, 13 float4
// loads issued up-front, launch_bounds(256,2) frees the allocator. Pack uses
// a 64x64 LDS tile transpose (coalesced reads) instead of stride-2KB scalars.
// gemm5 kernels unchanged from R8 (passed; ~63us combined).

typedef __bf16 bf16x8 __attribute__((ext_vector_type(8)));
typedef __bf16 bf16x4 __attribute__((ext_vector_type(4)));
typedef float f32x4 __attribute__((ext_vector_type(4)));

typedef __attribute__((address_space(3))) void lds_vp;
typedef const __attribute__((address_space(1))) void g_vp;

#define VMC(N) asm volatile("s_waitcnt vmcnt(" N ")" ::: "memory")

__device__ __forceinline__ void barrier_() {
  asm volatile("" ::: "memory");
  __builtin_amdgcn_s_barrier();
  asm volatile("" ::: "memory");
}

__device__ __forceinline__ float sigmoidf_(float x) { return 1.f / (1.f + expf(-x)); }

// ---------------- prep (8 cols/thread) + pack (LDS transpose) ----------------
__global__ __launch_bounds__(256, 2) void prep_pack_k(
    const float* __restrict__ inp, const float* __restrict__ h_prev,
    const float* __restrict__ gxd, const float* __restrict__ ghd,
    const float* __restrict__ mimp, __bf16* __restrict__ A1,
    const float* __restrict__ Wz, const float* __restrict__ Uz,
    const float* __restrict__ Wr, const float* __restrict__ Ur,
    const float* __restrict__ Wh, const float* __restrict__ Uh,
    __bf16* __restrict__ Wzr, __bf16* __restrict__ Wht) {
  __shared__ __bf16 T[64][65];
  int tid = threadIdx.x;
  if (blockIdx.x < 4096) {
    int idx = blockIdx.x * 256 + tid;
    int row = idx >> 6;
    int c8 = (idx & 63) << 3;
    const float* ir = inp + (size_t)row * 1536 + c8;
    float xx[8], mm[8], dd[8], hh[8], gx[8], gh[8], mi[8];
    *(float4*)&xx[0] = *(const float4*)(ir);
    *(float4*)&xx[4] = *(const float4*)(ir + 4);
    *(float4*)&mm[0] = *(const float4*)(ir + 512);
    *(float4*)&mm[4] = *(const float4*)(ir + 516);
    *(float4*)&dd[0] = *(const float4*)(ir + 1024);
    *(float4*)&dd[4] = *(const float4*)(ir + 1028);
    *(float4*)&hh[0] = *(const float4*)(h_prev + (size_t)row * 512 + c8);
    *(float4*)&hh[4] = *(const float4*)(h_prev + (size_t)row * 512 + c8 + 4);
    *(float4*)&gx[0] = *(const float4*)(gxd + c8);
    *(float4*)&gx[4] = *(const float4*)(gxd + c8 + 4);
    *(float4*)&gh[0] = *(const float4*)(ghd + c8);
    *(float4*)&gh[4] = *(const float4*)(ghd + c8 + 4);
    *(float4*)&mi[0] = *(const float4*)(mimp + c8);
    *(float4*)&mi[4] = *(const float4*)(mimp + c8 + 4);
    bf16x8 xo, ho;
#pragma unroll
    for (int j = 0; j < 8; ++j) {
      float g  = expf(-fmaxf(0.f, gx[j]) * dd[j]);
      float xd = mm[j] * xx[j] + (1.f - mm[j]) * (g * xx[j] + (1.f - g) * mi[j]);
      float gg = expf(-fmaxf(0.f, gh[j]) * dd[j]);
      float hd = gg * hh[j];
      xo[j] = (__bf16)xd;
      ho[j] = (__bf16)hd;
    }
    *(bf16x8*)(A1 + (size_t)row * 1024 + c8) = xo;
    *(bf16x8*)(A1 + (size_t)row * 1024 + 512 + c8) = ho;
  } else {
    // pack one 64x64 (k,n) tile, transposed, into dst[n][k] (ldk=1024)
    int bid = blockIdx.x - 4096;
    const float* S;
    __bf16* dst;
    int tk, tn, nadj;
    if (bid < 256) {           // Wzr: 16 k-tiles x 16 n-tiles
      tk = (bid >> 4) * 64; tn = (bid & 15) * 64;
      bool khi = tk >= 512, nhi = tn >= 512;
      S = nhi ? (khi ? Ur : Wr) : (khi ? Uz : Wz);
      nadj = nhi ? 512 : 0;
      dst = Wzr;
    } else {                   // Wht: 16 k-tiles x 8 n-tiles
      int b2 = bid - 256;
      tk = (b2 >> 3) * 64; tn = (b2 & 7) * 64;
      S = (tk >= 512) ? Uh : Wh;
      nadj = 0;
      dst = Wht;
    }
    int kadj = (tk >= 512) ? 512 : 0;
    int kl = tid >> 4, n4 = (tid & 15) << 2;
#pragma unroll
    for (int rr = 0; rr < 4; ++rr) {
      int k = rr * 16 + kl;
      float4 v = *(const float4*)(S + (size_t)(tk - kadj + k) * 512 + (tn - nadj) + n4);
      T[k][n4 + 0] = (__bf16)v.x;
      T[k][n4 + 1] = (__bf16)v.y;
      T[k][n4 + 2] = (__bf16)v.z;
      T[k][n4 + 3] = (__bf16)v.w;
    }
    __syncthreads();
    int k0 = (tid & 7) * 8;
#pragma unroll
    for (int h = 0; h < 2; ++h) {
      int nl = (tid >> 3) + h * 32;
      bf16x8 v;
#pragma unroll
      for (int i = 0; i < 8; ++i) v[i] = T[k0 + i][nl];
      *(bf16x8*)(dst + (size_t)(tn + nl) * 1024 + tk + k0) = v;
    }
  }
}

// ---------------- 3-buffer GEMM (BM=256, BK=32, one block-round) ----------------
// LDS packed layout (16B units): logical element (row m, 16B k-chunk ku in 0..3)
// stored at unit (m>>1)*8 + (((m&1)*4 + ku) ^ ((m>>1)&7)).
// Staging writes linear units; per-lane global source applies the inverse map.

template <int MODE>
__global__ __launch_bounds__(512, 1) void gemm5_k(
    const __bf16* __restrict__ A1, const __bf16* __restrict__ RH,
    const __bf16* __restrict__ Bt,
    __bf16* __restrict__ Zb, __bf16* __restrict__ RHout,
    const float* __restrict__ bza, const float* __restrict__ bzb,
    float* __restrict__ out) {
  constexpr int NI = (MODE == 0) ? 8 : 4;     // n-frags per wave
  constexpr int BN = NI * 32;                 // 256 / 128
  constexpr int BUNITS = BN * 4;              // B 16B-units per tile
  constexpr int SBUF = 1024 + BUNITS;         // A 1024 | B
  __shared__ bf16x8 ldsv[3 * SBUF];           // 96KB / 72KB
  constexpr int NT = 32;                      // K=1024, BK=32
#define VMC_STEADY() do { if constexpr (MODE == 0) { VMC("4"); } else { VMC("3"); } } while (0)

  int bid = blockIdx.x;
  int swz = (bid & 7) * 32 + (bid >> 3);      // bijective XCD swizzle (256=8x32)
  int bm = swz >> 2, bn = swz & 3;            // 64 x 4
  int tid = threadIdx.x, lane = tid & 63, wid = tid >> 6;
  int wm = wid >> 1, wn = wid & 1;            // 4M x 2N waves: 64 x (NI*16)

  // per-lane staging source offsets (inverse of packed-swizzle map)
  auto inv = [&](int U, int ldb) {
    int r = U >> 3, s = (U & 7) ^ (r & 7);
    return (2 * r + (s >> 2)) * ldb + (s & 3) * 16;  // bytes
  };
  int UA0 = wid * 128 + lane, UA1 = UA0 + 64;
  int offA0 = inv(UA0, 2048), offA1 = inv(UA1, 2048);
  int offA0r = inv(UA0, 1024), offA1r = inv(UA1, 1024);  // MODE1 RH half
  int UB0 = (MODE == 0) ? (wid * 128 + lane) : (wid * 64 + lane);
  int offB0 = inv(UB0, 2048);
  int offB1 = (MODE == 0) ? inv(UB0 + 64, 2048) : 0;
  int ldsB = (MODE == 0) ? (wid * 128) : (wid * 64);   // wave-uniform

  auto stage = [&](int t, int buf) {
    const char* gA;
    int oA0, oA1;
    if (MODE == 0 || t < 16) {
      gA = (const char*)A1 + (size_t)bm * 256 * 2048 + t * 64;
      oA0 = offA0; oA1 = offA1;
    } else {
      gA = (const char*)RH + (size_t)bm * 256 * 1024 + (t - 16) * 64;
      oA0 = offA0r; oA1 = offA1r;
    }
    __builtin_amdgcn_global_load_lds((g_vp*)(gA + oA0),
        (lds_vp*)(ldsv + buf * SBUF + wid * 128), 16, 0, 0);
    __builtin_amdgcn_global_load_lds((g_vp*)(gA + oA1),
        (lds_vp*)(ldsv + buf * SBUF + wid * 128 + 64), 16, 0, 0);
    const char* gB = (const char*)Bt + (size_t)bn * BN * 2048 + t * 64;
    __builtin_amdgcn_global_load_lds((g_vp*)(gB + offB0),
        (lds_vp*)(ldsv + buf * SBUF + 1024 + ldsB), 16, 0, 0);
    if constexpr (MODE == 0) {
      __builtin_amdgcn_global_load_lds((g_vp*)(gB + offB1),
          (lds_vp*)(ldsv + buf * SBUF + 1024 + ldsB + 64), 16, 0, 0);
    }
  };

  // fragment read bases (16B units), loop-invariant
  int lr = (lane & 15) >> 1;
  int lo = ((lane & 1) << 2) | (lane >> 4);
  int aoff = lr * 8 + (lo ^ lr);
  int aB = wm * 256 + aoff;                   // + mf*64
  int bB = 1024 + wn * (NI * 64) + aoff;      // + nf*64

  f32x4 acc[4][NI] = {};

  stage(0, 0);
  stage(1, 1);
  VMC_STEADY();
  barrier_();

  int rb = 0, sb = 2;
  for (int t = 0; t < NT; ++t) {
    int base = rb * SBUF;
    if (t + 2 < NT) stage(t + 2, sb);

    bf16x8 bf[NI];
#pragma unroll
    for (int nf = 0; nf < NI; ++nf) bf[nf] = ldsv[base + bB + nf * 64];
    __builtin_amdgcn_s_setprio(1);
#pragma unroll
    for (int mf = 0; mf < 4; ++mf) {
      bf16x8 a = ldsv[base + aB + mf * 64];
#pragma unroll
      for (int nf = 0; nf < NI; ++nf)
        acc[mf][nf] = __builtin_amdgcn_mfma_f32_16x16x32_bf16(a, bf[nf],
                                                              acc[mf][nf], 0, 0, 0);
    }
    __builtin_amdgcn_s_setprio(0);

    if (t + 2 < NT) { VMC_STEADY(); }
    else if (t + 1 < NT) { VMC("0"); }
    if (t + 1 < NT) barrier_();
    rb = (rb == 2) ? 0 : rb + 1;
    sb = (sb == 2) ? 0 : sb + 1;
  }

  // ---------------- epilogue ----------------
  int col16 = lane & 15, rgrp = lane >> 4;
#pragma unroll
  for (int mf = 0; mf < 4; ++mf) {
    int grow0 = bm * 256 + wm * 64 + mf * 16 + rgrp * 4;
#pragma unroll
    for (int nf = 0; nf < NI; ++nf) {
      int gc = bn * BN + wn * (NI * 16) + nf * 16 + col16;
      if constexpr (MODE == 0) {
        if (gc < 512) {  // z columns (nf-uniform: tile never straddles 512)
          float b = bza[gc];
#pragma unroll
          for (int j = 0; j < 4; ++j) {
            float z = sigmoidf_(acc[mf][nf][j] + b);
            Zb[(size_t)(grow0 + j) * 512 + gc] = (__bf16)z;
          }
        } else {       // r columns
          int c = gc - 512;
          float b = bzb[c];
#pragma unroll
          for (int j = 0; j < 4; ++j) {
            int grow = grow0 + j;
            float r = sigmoidf_(acc[mf][nf][j] + b);
            float hd = (float)A1[(size_t)grow * 1024 + 512 + c];
            RHout[(size_t)grow * 512 + c] = (__bf16)(r * hd);
          }
        }
      } else {
        float b = bza[gc];
#pragma unroll
        for (int j = 0; j < 4; ++j) {
          int grow = grow0 + j;
          float hh = tanhf(acc[mf][nf][j] + b);
          float hd = (float)A1[(size_t)grow * 1024 + 512 + gc];
          float z = (float)Zb[(size_t)grow * 512 + gc];
          out[(size_t)grow * 512 + gc] = (1.f - z) * hd + z * hh;
        }
      }
    }
  }
}

// ---------------- launch ----------------
extern "C" void kernel_launch(void* const* d_in, const int* in_sizes, int n_in,
                              void* d_out, int out_size, void* d_ws, size_t ws_size,
                              hipStream_t stream) {
  const float* inputs = (const float*)d_in[0];
  const float* h_prev = (const float*)d_in[1];
  const float* W_z = (const float*)d_in[2];
  const float* U_z = (const float*)d_in[3];
  const float* b_z = (const float*)d_in[4];
  const float* W_r = (const float*)d_in[5];
  const float* U_r = (const float*)d_in[6];
  const float* b_r = (const float*)d_in[7];
  const float* W_h = (const float*)d_in[8];
  const float* U_h = (const float*)d_in[9];
  const float* b_h = (const float*)d_in[10];
  const float* gxd = (const float*)d_in[11];
  const float* ghd = (const float*)d_in[12];
  const float* mimp = (const float*)d_in[13];
  float* out = (float*)d_out;

  char* ws = (char*)d_ws;
  __bf16* A1  = (__bf16*)(ws);                  // 16384x1024 bf16 = 32MB
  __bf16* RH  = (__bf16*)(ws + 33554432);       // 16384x512 bf16 = 16MB
  __bf16* Zb  = (__bf16*)(ws + 50331648);       // 16384x512 bf16 = 16MB
  __bf16* Wzr = (__bf16*)(ws + 67108864);       // 1024x1024 bf16 = 2MB
  __bf16* Wht = (__bf16*)(ws + 69206016);       // 512x1024 bf16  = 1MB

  prep_pack_k<<<4480, 256, 0, stream>>>(inputs, h_prev, gxd, ghd, mimp, A1,
                                        W_z, U_z, W_r, U_r, W_h, U_h, Wzr, Wht);
  gemm5_k<0><<<256, 512, 0, stream>>>(A1, RH, Wzr, Zb, RH, b_z, b_r, nullptr);
  gemm5_k<1><<<256, 512, 0, stream>>>(A1, RH, Wht, Zb, nullptr, b_h, nullptr, out);
}